// Round 9
// baseline (2183.992 us; speedup 1.0000x reference)
//
#include <hip/hip_runtime.h>
#include <math.h>

#define KTOP 2000
#define MAXOUT 500
#define CANDCAP 4096          // candidate capacity (global buffers)
#define NSEL 3600             // approx-score rank margin for selection
#define RC2 16                // candidates per rescore block (256 groups)

typedef __attribute__((ext_vector_type(8))) short short8;
typedef __attribute__((ext_vector_type(4))) float f32x4;

__device__ __forceinline__ unsigned short f2bf(float f) {
  unsigned int u = __float_as_uint(f);
  unsigned int r = ((u >> 16) & 1u) + 0x7FFFu;
  return (unsigned short)((u + r) >> 16);
}

// ---------------------------------------------------------------------------
// transpose+convert: W[K][N] f32 -> WT[N][K] bf16.  grid (K/32, N/32), 256 thr
// ---------------------------------------------------------------------------
__global__ __launch_bounds__(256) void transpose_bf16_kernel(
    const float* __restrict__ W, unsigned short* __restrict__ WT, int K, int N)
{
  __shared__ float t[32][33];
  const int k0 = blockIdx.x << 5, n0 = blockIdx.y << 5;
  const int tid = threadIdx.x;
  const int r = tid >> 5, c = tid & 31;
#pragma unroll
  for (int p = 0; p < 4; ++p)
    t[r + (p << 3)][c] = W[(size_t)(k0 + r + (p << 3)) * N + n0 + c];
  __syncthreads();
#pragma unroll
  for (int p = 0; p < 4; ++p)
    WT[(size_t)(n0 + r + (p << 3)) * K + k0 + c] = f2bf(t[c][r + (p << 3)]);
}

// ---------------------------------------------------------------------------
// prep WiB: Wi[288][64] f32 -> WiB[tap(9)][co(64)][ci(32)] bf16
// ---------------------------------------------------------------------------
__global__ __launch_bounds__(256) void prep_wib_kernel(
    const float* __restrict__ Wi, unsigned short* __restrict__ WiB)
{
  const int t = blockIdx.x * 256 + threadIdx.x;
  if (t < 9 * 64 * 32) {
    const int tap = t / 2048, r = t & 2047, co = r >> 5, ci = r & 31;
    WiB[t] = f2bf(Wi[((size_t)tap * 32 + ci) * 64 + co]);
  }
}

// ---------------------------------------------------------------------------
// conv1 via bf16 MFMA: 3x3 128->1024 + bias + relu -> x1b (bf16, chunk-local)
// ---------------------------------------------------------------------------
#define LSTR 72   // LDS row stride in bf16 elements (144 B)
__global__ __launch_bounds__(256) void conv1_mfma(
    const float* __restrict__ df, const unsigned short* __restrict__ WcT,
    const float* __restrict__ bc, unsigned short* __restrict__ x1b, int pt0)
{
  __shared__ __align__(16) unsigned short As[128 * LSTR];
  __shared__ __align__(16) unsigned short Bs[128 * LSTR];
  const int tid = threadIdx.x;
  const int n0 = blockIdx.x << 7;
  const int m0 = blockIdx.y << 7;
  const int Pbase = (pt0 << 6) + m0;
  const int ybase = Pbase >> 8, x0 = Pbase & 255;
  const int wv = tid >> 6, lane = tid & 63;
  const int wm = (wv & 1) << 6, wn = (wv >> 1) << 6;
  const int l15 = lane & 15, quad = lane >> 4;

  f32x4 acc[4][4];
  const f32x4 z4 = {0.f, 0.f, 0.f, 0.f};
#pragma unroll
  for (int i = 0; i < 4; ++i)
#pragma unroll
    for (int j = 0; j < 4; ++j) acc[i][j] = z4;

  for (int kc = 0; kc < 18; ++kc) {
    const int tap = kc >> 1, ci0 = (kc & 1) << 6;
    const int dy = tap / 3 - 1, dx = tap % 3 - 1;
    const int gy = ybase + dy;
    const bool yok = (gy >= 0 && gy < 256);
#pragma unroll
    for (int p = 0; p < 8; ++p) {
      const int r = (p << 4) + (tid >> 4);
      const int c4 = tid & 15;
      const int gx = x0 + r + dx;
      float4 v = make_float4(0.f, 0.f, 0.f, 0.f);
      if (yok && gx >= 0 && gx < 256)
        v = *(const float4*)&df[((size_t)((gy << 8) + gx)) * 128 + ci0 + (c4 << 2)];
      const unsigned int lo = (unsigned int)f2bf(v.x) | ((unsigned int)f2bf(v.y) << 16);
      const unsigned int hi = (unsigned int)f2bf(v.z) | ((unsigned int)f2bf(v.w) << 16);
      *(uint2*)&As[r * LSTR + (c4 << 2)] = make_uint2(lo, hi);
    }
#pragma unroll
    for (int p = 0; p < 4; ++p) {
      const int n = (p << 5) + (tid >> 3);
      const int kg = (tid & 7) << 3;
      const uint4 w = *(const uint4*)&WcT[(size_t)(n0 + n) * 1152 + kc * 64 + kg];
      *(uint4*)&Bs[n * LSTR + kg] = w;
    }
    __syncthreads();
#pragma unroll
    for (int s = 0; s < 2; ++s) {
      short8 a[4], b[4];
#pragma unroll
      for (int i = 0; i < 4; ++i)
        a[i] = *(short8*)&As[(wm + (i << 4) + l15) * LSTR + (s << 5) + (quad << 3)];
#pragma unroll
      for (int i = 0; i < 4; ++i)
        b[i] = *(short8*)&Bs[(wn + (i << 4) + l15) * LSTR + (s << 5) + (quad << 3)];
#pragma unroll
      for (int i = 0; i < 4; ++i)
#pragma unroll
        for (int j = 0; j < 4; ++j)
          acc[i][j] = __builtin_amdgcn_mfma_f32_16x16x32_bf16(a[i], b[j], acc[i][j], 0, 0, 0);
    }
    __syncthreads();
  }
#pragma unroll
  for (int i = 0; i < 4; ++i)
#pragma unroll
    for (int j = 0; j < 4; ++j) {
      const int col = wn + (j << 4) + l15;
      const float bb = bc[n0 + col];
#pragma unroll
      for (int rg = 0; rg < 4; ++rg) {
        const int row = wm + (i << 4) + (quad << 2) + rg;
        const float v = fmaxf(acc[i][j][rg] + bb, 0.f);
        x1b[(size_t)(m0 + row) * 1024 + n0 + col] = f2bf(v);
      }
    }
}

// ---------------------------------------------------------------------------
// fc via bf16 MFMA: 1x1 1024->1024 + bias + relu, fused score partials.
// ---------------------------------------------------------------------------
__global__ __launch_bounds__(256) void fc_mfma(
    const unsigned short* __restrict__ x1b, const unsigned short* __restrict__ WfcT,
    const float* __restrict__ bfc, const float* __restrict__ Wsc,
    float* __restrict__ part, int pt0)
{
  __shared__ __align__(16) unsigned short As[128 * LSTR];
  __shared__ __align__(16) unsigned short Bs[128 * LSTR];
  const int tid = threadIdx.x;
  const int n0 = blockIdx.x << 7;
  const int m0 = blockIdx.y << 7;
  const int Pbase = (pt0 << 6) + m0;
  const int wv = tid >> 6, lane = tid & 63;
  const int wm = (wv & 1) << 6, wn = (wv >> 1) << 6;
  const int l15 = lane & 15, quad = lane >> 4;

  f32x4 acc[4][4];
  const f32x4 z4 = {0.f, 0.f, 0.f, 0.f};
#pragma unroll
  for (int i = 0; i < 4; ++i)
#pragma unroll
    for (int j = 0; j < 4; ++j) acc[i][j] = z4;

  for (int kc = 0; kc < 16; ++kc) {
#pragma unroll
    for (int p = 0; p < 4; ++p) {
      const int r = (p << 5) + (tid >> 3);
      const int kg = (tid & 7) << 3;
      const uint4 w = *(const uint4*)&x1b[(size_t)(m0 + r) * 1024 + kc * 64 + kg];
      *(uint4*)&As[r * LSTR + kg] = w;
    }
#pragma unroll
    for (int p = 0; p < 4; ++p) {
      const int n = (p << 5) + (tid >> 3);
      const int kg = (tid & 7) << 3;
      const uint4 w = *(const uint4*)&WfcT[(size_t)(n0 + n) * 1024 + kc * 64 + kg];
      *(uint4*)&Bs[n * LSTR + kg] = w;
    }
    __syncthreads();
#pragma unroll
    for (int s = 0; s < 2; ++s) {
      short8 a[4], b[4];
#pragma unroll
      for (int i = 0; i < 4; ++i)
        a[i] = *(short8*)&As[(wm + (i << 4) + l15) * LSTR + (s << 5) + (quad << 3)];
#pragma unroll
      for (int i = 0; i < 4; ++i)
        b[i] = *(short8*)&Bs[(wn + (i << 4) + l15) * LSTR + (s << 5) + (quad << 3)];
#pragma unroll
      for (int i = 0; i < 4; ++i)
#pragma unroll
        for (int j = 0; j < 4; ++j)
          acc[i][j] = __builtin_amdgcn_mfma_f32_16x16x32_bf16(a[i], b[j], acc[i][j], 0, 0, 0);
    }
    __syncthreads();
  }
  float wsv[4], bfv[4];
#pragma unroll
  for (int j = 0; j < 4; ++j) {
    const int col = n0 + wn + (j << 4) + l15;
    wsv[j] = Wsc[col];
    bfv[j] = bfc[col];
  }
  float* red = (float*)As;
#pragma unroll
  for (int i = 0; i < 4; ++i)
#pragma unroll
    for (int rg = 0; rg < 4; ++rg) {
      const int row = wm + (i << 4) + (quad << 2) + rg;
      float ps = 0.f;
#pragma unroll
      for (int j = 0; j < 4; ++j) {
        const float v = fmaxf(acc[i][j][rg] + bfv[j], 0.f);
        ps = fmaf(v, wsv[j], ps);
      }
      red[row * 33 + ((wv >> 1) << 4) + l15] = ps;
    }
  __syncthreads();
  if (tid < 128) {
    float s = 0.f;
#pragma unroll
    for (int sl = 0; sl < 32; ++sl) s += red[tid * 33 + sl];
    part[(size_t)blockIdx.x * 65536 + Pbase + tid] = s;
  }
}

// ---------------------------------------------------------------------------
// finalize: sum 8 partials, bias, sigmoid -> f32 approx scores (selection)
// ---------------------------------------------------------------------------
__global__ __launch_bounds__(256) void head_finalize_kernel(
    const float* __restrict__ part, const float* __restrict__ bs,
    float* __restrict__ scores)
{
  const int pix = blockIdx.x * 256 + threadIdx.x;
  float s = 0.f;
#pragma unroll
  for (int cb = 0; cb < 8; ++cb) s += part[(size_t)cb * 65536 + pix];
  s += bs[0];
  scores[pix] = 1.f / (1.f + expf(-s));
}

// ---------------------------------------------------------------------------
// select: radix-select NSEL-th approx score, then DETERMINISTIC prefix-scan
// compaction of all cells >= thr in ascending cell order (no atomics).
// ---------------------------------------------------------------------------
__global__ __launch_bounds__(1024) void select_kernel(
    const float* __restrict__ scores, unsigned int* __restrict__ cand_idx,
    unsigned int* __restrict__ cand_cnt)
{
  __shared__ unsigned int hist[256];
  __shared__ unsigned int sh_prefix;
  __shared__ int scan_s[1024];
  const int tid = threadIdx.x;

  unsigned int prefix = 0u;
  int need = NSEL;
  for (int byte = 3; byte >= 0; --byte) {
    if (tid < 256) hist[tid] = 0u;
    __syncthreads();
    const int sh = byte * 8;
    const unsigned int mhi = (byte == 3) ? 0u : (0xFFFFFFFFu << (sh + 8));
    for (int i = tid; i < 65536; i += 1024) {
      const unsigned int b = __float_as_uint(scores[i]);
      if ((b & mhi) == prefix) atomicAdd(&hist[(b >> sh) & 255u], 1u);
    }
    __syncthreads();
    if (tid == 0) {
      int cum = 0;
      for (int v = 255; v >= 0; --v) {
        const int c = (int)hist[v];
        if (cum + c >= need) { sh_prefix = prefix | ((unsigned)v << sh); break; }
        cum += c;
      }
      hist[0] = (unsigned int)cum;
    }
    __syncthreads();
    prefix = sh_prefix;
    need -= (int)hist[0];
    __syncthreads();
  }
  const float thr = __uint_as_float(prefix);

  // deterministic compaction: thread t owns cells [t*64, t*64+64)
  const int b0 = tid << 6;
  int my = 0;
  for (int k = 0; k < 64; ++k)
    if (scores[b0 + k] >= thr) ++my;
  scan_s[tid] = my;
  __syncthreads();
  for (int off = 1; off < 1024; off <<= 1) {
    const int a = scan_s[tid];
    const int b = (tid >= off) ? scan_s[tid - off] : 0;
    __syncthreads();
    scan_s[tid] = a + b;
    __syncthreads();
  }
  int pos = scan_s[tid] - my;     // exclusive prefix
  const int total = scan_s[1023];
  for (int k = 0; k < 64; ++k) {
    if (scores[b0 + k] >= thr) {
      if (pos < CANDCAP) cand_idx[pos] = (unsigned int)(b0 + k);
      ++pos;
    }
  }
  if (tid == 0)
    *cand_cnt = (unsigned int)(total > CANDCAP ? CANDCAP : total);
}

// ---------------------------------------------------------------------------
// rescore_conv: f64 conv1 for RC2 candidates per block -> x1g (global f64).
// 1024 threads: thread owns co = tid (16 waves/CU, weight traffic unchanged).
// ---------------------------------------------------------------------------
__global__ __launch_bounds__(1024) void rescore_conv(
    const float* __restrict__ df, const float* __restrict__ Wc,
    const float* __restrict__ bc,
    const unsigned int* __restrict__ cand_idx,
    const unsigned int* __restrict__ cand_cnt,
    double* __restrict__ x1g)
{
  __shared__ float patt[RC2][132];
  const int cnt = (int)*cand_cnt;
  const int c0 = blockIdx.x * RC2;
  if (c0 >= cnt) return;
  const int tid = threadIdx.x;

  int rr[RC2], cc[RC2];
#pragma unroll
  for (int c = 0; c < RC2; ++c) {
    const int slot = (c0 + c < cnt) ? c0 + c : c0;
    const unsigned int idx = cand_idx[slot];
    rr[c] = (int)(idx >> 8); cc[c] = (int)(idx & 255u);
  }

  double acc[RC2];
#pragma unroll
  for (int c = 0; c < RC2; ++c) acc[c] = 0.0;

  for (int tap = 0; tap < 9; ++tap) {
    const int dy = tap / 3 - 1, dx = tap % 3 - 1;
    for (int t = tid; t < RC2 * 128; t += 1024) {
      const int c = t >> 7, ci = t & 127;
      const int gy = rr[c] + dy, gx = cc[c] + dx;
      float v = 0.f;
      if (gy >= 0 && gy < 256 && gx >= 0 && gx < 256)
        v = df[((size_t)((gy << 8) + gx)) * 128 + ci];
      patt[c][ci] = v;
    }
    __syncthreads();
    const float* wbase = &Wc[(size_t)(tap << 7) * 1024 + tid];
    float wf = *wbase;
    for (int ci = 0; ci < 128; ++ci) {
      const float wfn = (ci + 1 < 128) ? wbase[(size_t)(ci + 1) * 1024] : wf;
      const double w = (double)wf;
#pragma unroll
      for (int c = 0; c < RC2; ++c)
        acc[c] = fma(w, (double)patt[c][ci], acc[c]);
      wf = wfn;
    }
    __syncthreads();
  }
  const double b = (double)bc[tid];
#pragma unroll
  for (int c = 0; c < RC2; ++c) {
    if (c0 + c < cnt) {
      const double v = acc[c] + b;
      x1g[(size_t)(c0 + c) * 1024 + tid] = v > 0.0 ? v : 0.0;
    }
  }
}

// ---------------------------------------------------------------------------
// rescore_fc: f64 fc + heads for RC2 candidates per block, x1 from x1g.
// 1024 threads: thread owns co = tid; deterministic butterfly reduction.
// ---------------------------------------------------------------------------
__global__ __launch_bounds__(1024) void rescore_fc(
    const double* __restrict__ x1g, const float* __restrict__ Wfc,
    const float* __restrict__ bfc, const float* __restrict__ Wsc,
    const float* __restrict__ bs, const float* __restrict__ Wrg,
    const float* __restrict__ br,
    const unsigned int* __restrict__ cand_cnt,
    unsigned long long* __restrict__ cand_sb,
    double* __restrict__ cand_ry, double* __restrict__ cand_rx)
{
  __shared__ double xbuf[RC2][264];    // 33.8 KB
  __shared__ double redw[48];          // 16 waves x 3 heads
  const int cnt = (int)*cand_cnt;
  const int c0 = blockIdx.x * RC2;
  if (c0 >= cnt) return;
  const int tid = threadIdx.x;
  const int wave = tid >> 6, lane = tid & 63;

  double a2[RC2];
#pragma unroll
  for (int c = 0; c < RC2; ++c) a2[c] = 0.0;

  for (int kc = 0; kc < 4; ++kc) {
    __syncthreads();
    for (int t = tid; t < RC2 * 256; t += 1024) {
      const int c = t >> 8, k = t & 255;
      const int row = (c0 + c < cnt) ? c0 + c : c0;
      xbuf[c][k] = x1g[(size_t)row * 1024 + (kc << 8) + k];
    }
    __syncthreads();
    const float* wbase = &Wfc[(size_t)(kc << 8) * 1024 + tid];
    float wf = *wbase;
    for (int kk = 0; kk < 256; ++kk) {
      const float wfn = (kk + 1 < 256) ? wbase[(size_t)(kk + 1) * 1024] : wf;
      const double w = (double)wf;
#pragma unroll
      for (int c = 0; c < RC2; ++c)
        a2[c] = fma(w, xbuf[c][kk], a2[c]);
      wf = wfn;
    }
  }

  const double bf = (double)bfc[tid];
  const double ws = (double)Wsc[tid];
  const double w0 = (double)Wrg[tid * 2], w1 = (double)Wrg[tid * 2 + 1];

  __syncthreads();
  for (int c = 0; c < RC2; ++c) {
    double v = a2[c] + bf;
    v = v > 0.0 ? v : 0.0;
    double s = v * ws, ry = v * w0, rx = v * w1;
    // deterministic butterfly reduce within wave (64 lanes)
#pragma unroll
    for (int off = 32; off > 0; off >>= 1) {
      s  += __shfl_xor(s, off, 64);
      ry += __shfl_xor(ry, off, 64);
      rx += __shfl_xor(rx, off, 64);
    }
    if (lane == 0) {
      redw[wave * 3 + 0] = s;
      redw[wave * 3 + 1] = ry;
      redw[wave * 3 + 2] = rx;
    }
    __syncthreads();
    if (tid == 0 && c0 + c < cnt) {
      double S = 0.0, RY = 0.0, RX = 0.0;
#pragma unroll
      for (int wq = 0; wq < 16; ++wq) {
        S  += redw[wq * 3 + 0];
        RY += redw[wq * 3 + 1];
        RX += redw[wq * 3 + 2];
      }
      const double lg = S + (double)bs[0];
      const double sg = 1.0 / (1.0 + exp(-lg));
      cand_sb[c0 + c] = (unsigned long long)__double_as_longlong(sg);
      cand_ry[c0 + c] = RY + (double)br[0];
      cand_rx[c0 + c] = RX + (double)br[1];
    }
    __syncthreads();
  }
}

// ---------------------------------------------------------------------------
// proposal: f64 radix-select top-2000, DETERMINISTIC compaction (ascending
// slot = ascending cell), bitonic sort with (score desc, slot asc) tie-break,
// f64 NMS, emit.  Single block, 1024 threads.
// ---------------------------------------------------------------------------
__global__ __launch_bounds__(1024) void proposal_kernel(
    const unsigned int* __restrict__ cand_idx,
    const unsigned int* __restrict__ cand_cnt,
    const unsigned long long* __restrict__ cand_sb,
    const double* __restrict__ cand_ry, const double* __restrict__ cand_rx,
    unsigned int* __restrict__ cellrank, unsigned int* __restrict__ nbrg,
    double* __restrict__ cyg, double* __restrict__ cxg,
    int* __restrict__ startb, float* __restrict__ out_ps,
    float* __restrict__ out_dec)
{
  __shared__ unsigned long long sk[2048];
  __shared__ unsigned int si[2048];
  __shared__ unsigned int hist[256];
  __shared__ unsigned long long sh_pref;
  __shared__ unsigned char kept[2048];
  __shared__ unsigned char nbrc[2048];
  __shared__ int scan[2048];
  __shared__ volatile unsigned int changed;
  __shared__ int sh_maxreg;

  const int tid = threadIdx.x;
  const int cnt = (int)*cand_cnt;

  for (int i = tid; i < 65536; i += 1024) cellrank[i] = 0xFFFFFFFFu;

  // ---- radix-select the 2000th-largest f64-score bit pattern
  unsigned long long prefix = 0ull;
  int need = KTOP;
  for (int byte = 7; byte >= 0; --byte) {
    if (tid < 256) hist[tid] = 0u;
    __syncthreads();
    const int sh = byte * 8;
    const unsigned long long mhi =
        (byte == 7) ? 0ull : (0xFFFFFFFFFFFFFFFFull << (sh + 8));
    for (int i = tid; i < cnt; i += 1024) {
      const unsigned long long k = cand_sb[i];
      if ((k & mhi) == prefix) atomicAdd(&hist[(unsigned int)((k >> sh) & 255u)], 1u);
    }
    __syncthreads();
    if (tid == 0) {
      int cum = 0;
      for (int v = 255; v >= 0; --v) {
        const int c = (int)hist[v];
        if (cum + c >= need) {
          sh_pref = prefix | ((unsigned long long)(unsigned)v << sh);
          break;
        }
        cum += c;
      }
      hist[0] = (unsigned int)cum;
    }
    __syncthreads();
    prefix = sh_pref;
    need -= (int)hist[0];
    __syncthreads();
  }
  const unsigned long long T = prefix;

  // ---- deterministic compaction: thread t owns slots [4t, 4t+4)
  const int s0 = tid << 2;
  unsigned long long kv[4];
  int ca = 0, cb = 0;
#pragma unroll
  for (int q = 0; q < 4; ++q) {
    const int s = s0 + q;
    kv[q] = (s < cnt) ? cand_sb[s] : 0ull;
    if (s < cnt) { if (kv[q] > T) ++ca; else if (kv[q] == T) ++cb; }
  }
  scan[tid] = ca;
  __syncthreads();
  for (int off = 1; off < 1024; off <<= 1) {
    const int a = scan[tid];
    const int b = (tid >= off) ? scan[tid - off] : 0;
    __syncthreads();
    scan[tid] = a + b;
    __syncthreads();
  }
  int posA = scan[tid] - ca;         // exclusive
  const int atot = scan[1023];
  __syncthreads();
  scan[tid] = cb;
  __syncthreads();
  for (int off = 1; off < 1024; off <<= 1) {
    const int a = scan[tid];
    const int b = (tid >= off) ? scan[tid - off] : 0;
    __syncthreads();
    scan[tid] = a + b;
    __syncthreads();
  }
  int posB = atot + (scan[tid] - cb);
  __syncthreads();
#pragma unroll
  for (int q = 0; q < 4; ++q) {
    const int s = s0 + q;
    if (s < cnt) {
      if (kv[q] > T) {
        sk[posA] = kv[q]; si[posA] = (unsigned int)s; ++posA;
      } else if (kv[q] == T) {
        if (posB < KTOP) { sk[posB] = kv[q]; si[posB] = (unsigned int)s; }
        ++posB;
      }
    }
  }
  __syncthreads();
  for (int i = tid; i < 2048; i += 1024)
    if (i >= KTOP) { sk[i] = 0ull; si[i] = 0u; }
  if (tid == 0) sh_maxreg = 0;
  __syncthreads();

  // ---- bitonic sort 2048 descending by (score bits, then ascending slot)
  for (int k = 2; k <= 2048; k <<= 1) {
    for (int j = k >> 1; j > 0; j >>= 1) {
      const int i = (tid & (j - 1)) | ((tid & ~(j - 1)) << 1);
      const int ixj = i | j;
      const unsigned long long a = sk[i], b = sk[ixj];
      const unsigned int ia = si[i], ib = si[ixj];
      const bool up = ((i & k) == 0);
      const bool lt = (a < b) || (a == b && ia > ib);
      const bool gt = (a > b) || (a == b && ia < ib);
      if (up ? lt : gt) {
        sk[i] = b; sk[ixj] = a;
        si[i] = ib; si[ixj] = ia;
      }
      __syncthreads();
    }
  }

  // ---- decode top-2000 (f64)
  for (int r = tid; r < KTOP; r += 1024) {
    const unsigned int slot = si[r];
    const unsigned int idx = cand_idx[slot];
    const int row = (int)(idx >> 8), col = (int)(idx & 255u);
    const double ry = cand_ry[slot], rx = cand_rx[slot];
    cyg[r] = ((double)row + 0.5) + ry;
    cxg[r] = ((double)col + 0.5) + rx;
    kept[r] = 1; nbrc[r] = 0;
    cellrank[idx] = (unsigned int)r;
    atomicMax(&sh_maxreg, __float_as_int((float)fabs(ry)));
    atomicMax(&sh_maxreg, __float_as_int((float)fabs(rx)));
  }
  __syncthreads();
  const float maxreg = __int_as_float(sh_maxreg);
  int rad = (int)(1.0f + 2.0f * maxreg) + 1;
  if (rad > 8) rad = 8;
  if (rad < 1) rad = 1;

  // ---- earlier-close neighbor lists (f64 distances, no contraction)
  for (int r = tid; r < KTOP; r += 1024) {
    const unsigned int idx = cand_idx[si[r]];
    const int row = (int)(idx >> 8), col = (int)(idx & 255u);
    int n = 0;
    const double pyr = cyg[r], pxr = cxg[r];
    for (int dy = -rad; dy <= rad; ++dy) {
      const int yy = row + dy; if (yy < 0 || yy >= 256) continue;
      for (int dx = -rad; dx <= rad; ++dx) {
        if (dy == 0 && dx == 0) continue;
        const int xx = col + dx; if (xx < 0 || xx >= 256) continue;
        const unsigned int q = cellrank[yy * 256 + xx];
        if (q < (unsigned int)r) {
          const double t1 = __dsub_rn(pyr, cyg[q]);
          const double t2 = __dsub_rn(pxr, cxg[q]);
          const double d2 = __dadd_rn(__dmul_rn(t1, t1), __dmul_rn(t2, t2));
          if (d2 < 1.0) { if (n < 16) nbrg[(size_t)r * 16 + n] = q; ++n; }
        }
      }
    }
    nbrc[r] = (unsigned char)(n < 16 ? n : 16);
  }
  __syncthreads();

  // ---- fixpoint == sequential NMS (unique fixpoint on rank-DAG)
  for (int it = 0; it < 4096; ++it) {
    __syncthreads();
    if (tid == 0) changed = 0;
    __syncthreads();
    for (int r = tid; r < KTOP; r += 1024) {
      const int nc = nbrc[r];
      if (nc) {
        int kvv = 1;
        for (int t = 0; t < nc; ++t)
          if (kept[nbrg[(size_t)r * 16 + t]]) { kvv = 0; break; }
        if (kvv != (int)kept[r]) { kept[r] = (unsigned char)kvv; changed = 1; }
      }
    }
    __syncthreads();
    if (changed == 0) break;
  }

  // ---- inclusive prefix scan of kept
  scan[tid]        = (tid < KTOP) ? (int)kept[tid] : 0;
  scan[tid + 1024] = (tid + 1024 < KTOP) ? (int)kept[tid + 1024] : 0;
  __syncthreads();
  for (int off = 1; off < 2048; off <<= 1) {
    const int a0 = scan[tid];
    const int b0 = (tid >= off) ? scan[tid - off] : 0;
    const int a1 = scan[tid + 1024];
    const int b1 = (tid + 1024 >= off) ? scan[tid + 1024 - off] : 0;
    __syncthreads();
    scan[tid] = a0 + b0;
    scan[tid + 1024] = a1 + b1;
    __syncthreads();
  }
  const int total = scan[KTOP - 1];

  // ---- emit
  for (int r = tid; r < KTOP; r += 1024) {
    int slot = -1;
    if (kept[r]) { const int p = scan[r] - 1; if (p < MAXOUT) slot = p; }
    else { const int p = total + (r - scan[r]); if (p < MAXOUT) slot = p; }
    if (slot >= 0) {
      const double sg = __longlong_as_double((long long)sk[r]);
      out_ps[slot] = kept[r] ? (float)sg : -1.0f;
      const double py = cyg[r], px = cxg[r];
      out_dec[slot * 2]     = (float)(py * 4.0);
      out_dec[slot * 2 + 1] = (float)(px * 4.0);
      int sy = (int)rint(py * 2.0 - 24.0);
      int sx = (int)rint(px * 2.0 - 24.0);
      sy = sy < 0 ? 0 : (sy > 464 ? 464 : sy);
      sx = sx < 0 ? 0 : (sx > 464 ? 464 : sx);
      startb[slot * 2] = sy; startb[slot * 2 + 1] = sx;
    }
  }
}

// ---------------------------------------------------------------------------
// conv_i via bf16 MFMA: 3x3 32->64 + relu on 48x48 crops -> h (bf16).
// ---------------------------------------------------------------------------
#define ISTR 40   // input pixel stride in bf16 elems (80 B)
__global__ __launch_bounds__(256) void conv_i_mfma(
    const float* __restrict__ seg, const unsigned short* __restrict__ WiB,
    const float* __restrict__ bi, const int* __restrict__ startb,
    unsigned short* __restrict__ h, int inst0)
{
  __shared__ __align__(16) unsigned short ins[500 * ISTR];   // 40 KB (reused)
  const int li = blockIdx.y;
  const int inst = inst0 + li;
  const int tile = blockIdx.x;              // 0..5
  const int r0 = tile << 3;
  const int tid = threadIdx.x;
  const int sy = startb[inst * 2], sx = startb[inst * 2 + 1];

  for (int p = tid; p < 500; p += 256) {
    const int rr = p / 50, cc2 = p - rr * 50;
    const int ir = r0 - 1 + rr, ic = cc2 - 1;
    unsigned short* dst = &ins[p * ISTR];
    if (ir >= 0 && ir < 48 && ic >= 0 && ic < 48) {
      const float* src = &seg[((size_t)(sy + ir) * 512 + (sx + ic)) * 32];
#pragma unroll
      for (int q = 0; q < 8; ++q) {
        const float4 v = *(const float4*)&src[q << 2];
        const unsigned int lo = (unsigned int)f2bf(v.x) | ((unsigned int)f2bf(v.y) << 16);
        const unsigned int hi = (unsigned int)f2bf(v.z) | ((unsigned int)f2bf(v.w) << 16);
        *(uint2*)&dst[q << 2] = make_uint2(lo, hi);
      }
    } else {
#pragma unroll
      for (int q = 0; q < 4; ++q) *(uint4*)&dst[q << 3] = make_uint4(0, 0, 0, 0);
    }
  }
  __syncthreads();

  const int wv = tid >> 6, lane = tid & 63;
  const int l15 = lane & 15, quad = lane >> 4;
  const int wmb = wv * 96;

  int pbase[6];
#pragma unroll
  for (int i = 0; i < 6; ++i) {
    const int m = wmb + (i << 4) + l15;
    pbase[i] = (m / 48 + 1) * 50 + (m % 48) + 1;
  }

  f32x4 acc[6][4];
  const f32x4 z4 = {0.f, 0.f, 0.f, 0.f};
#pragma unroll
  for (int i = 0; i < 6; ++i)
#pragma unroll
    for (int j = 0; j < 4; ++j) acc[i][j] = z4;

  for (int tap = 0; tap < 9; ++tap) {
    const int off = (tap / 3 - 1) * 50 + (tap % 3 - 1);
    short8 b[4];
#pragma unroll
    for (int j = 0; j < 4; ++j)
      b[j] = *(const short8*)&WiB[((tap << 6) + (j << 4) + l15) * 32 + (quad << 3)];
#pragma unroll
    for (int i = 0; i < 6; ++i) {
      const short8 a = *(const short8*)&ins[(pbase[i] + off) * ISTR + (quad << 3)];
#pragma unroll
      for (int j = 0; j < 4; ++j)
        acc[i][j] = __builtin_amdgcn_mfma_f32_16x16x32_bf16(a, b[j], acc[i][j], 0, 0, 0);
    }
  }

  float bv[4];
#pragma unroll
  for (int j = 0; j < 4; ++j) bv[j] = bi[(j << 4) + l15];

  for (int half = 0; half < 2; ++half) {
    __syncthreads();
    if ((wv >> 1) == half) {
#pragma unroll
      for (int i = 0; i < 6; ++i)
#pragma unroll
        for (int j = 0; j < 4; ++j)
#pragma unroll
          for (int rg = 0; rg < 4; ++rg) {
            const int m = wmb + (i << 4) + (quad << 2) + rg;
            const int pp = m - half * 192;
            const float v = fmaxf(acc[i][j][rg] + bv[j], 0.f);
            ins[pp * 72 + (j << 4) + l15] = f2bf(v);
          }
    }
    __syncthreads();
    for (int t = tid; t < 192 * 8; t += 256) {
      const int pp = t >> 3, c8 = t & 7;
      const uint4 v = *(const uint4*)&ins[pp * 72 + (c8 << 3)];
      *(uint4*)&h[((size_t)li * 2304 + (tile * 384 + half * 192 + pp)) * 64 + (c8 << 3)] = v;
    }
  }
}

// ---------------------------------------------------------------------------
// conv_o: 3x3, 64->1 + sigmoid on bf16 h; emits instance_coords.
// ---------------------------------------------------------------------------
__global__ __launch_bounds__(256) void conv_o_kernel(
    const unsigned short* __restrict__ h, const float* __restrict__ Wo,
    const float* __restrict__ bo, const int* __restrict__ startb,
    float* __restrict__ out_io, float* __restrict__ out_ic, int inst0)
{
  __shared__ __align__(16) unsigned short hs[324 * 72];   // 46.7 KB
  __shared__ float wos[576];
  const int li = blockIdx.y;
  const int inst = inst0 + li;
  const int tile = blockIdx.x;
  const int ty0 = (tile / 3) << 4;
  const int tx0 = (tile % 3) << 4;
  const int tid = threadIdx.x;

  for (int i = tid; i < 576; i += 256) wos[i] = Wo[i];
  for (int p = tid; p < 324; p += 256) {
    const int iy = p / 18, ix = p - iy * 18;
    const int gy = ty0 - 1 + iy, gx = tx0 - 1 + ix;
    unsigned short* dst = &hs[p * 72];
    if (gy >= 0 && gy < 48 && gx >= 0 && gx < 48) {
      const unsigned short* src = &h[((size_t)li * 2304 + gy * 48 + gx) * 64];
#pragma unroll
      for (int q = 0; q < 8; ++q) *(uint4*)&dst[q << 3] = *(const uint4*)&src[q << 3];
    } else {
#pragma unroll
      for (int q = 0; q < 8; ++q) *(uint4*)&dst[q << 3] = make_uint4(0, 0, 0, 0);
    }
  }
  __syncthreads();

  const int ly = tid >> 4, lx = tid & 15;
  float a = 0.f;
#pragma unroll
  for (int ky = 0; ky < 3; ++ky)
#pragma unroll
    for (int kx = 0; kx < 3; ++kx) {
      const unsigned short* hp = &hs[((ly + ky) * 18 + lx + kx) * 72];
      const float* wp = &wos[(ky * 3 + kx) << 6];
#pragma unroll
      for (int c8 = 0; c8 < 8; ++c8) {
        const uint4 hv = *(const uint4*)&hp[c8 << 3];
        const unsigned int uu[4] = {hv.x, hv.y, hv.z, hv.w};
#pragma unroll
        for (int e = 0; e < 4; ++e) {
          const float f0 = __uint_as_float(uu[e] << 16);
          const float f1 = __uint_as_float(uu[e] & 0xFFFF0000u);
          a = fmaf(f0, wp[(c8 << 3) + (e << 1)], a);
          a = fmaf(f1, wp[(c8 << 3) + (e << 1) + 1], a);
        }
      }
    }
  a += bo[0];
  const float o = 1.f / (1.f + expf(-a));
  const int gy = ty0 + ly, gx = tx0 + lx;
  const size_t p = ((size_t)inst * 48 + gy) * 48 + gx;
  out_io[p] = o;
  const int sy = startb[inst * 2], sx = startb[inst * 2 + 1];
  out_ic[p * 2]     = (float)(sy + gy);
  out_ic[p * 2 + 1] = (float)(sx + gx);
}

// ---------------------------------------------------------------------------
extern "C" void kernel_launch(void* const* d_in, const int* in_sizes, int n_in,
                              void* d_out, int out_size, void* d_ws, size_t ws_size,
                              hipStream_t stream)
{
  const float* df  = (const float*)d_in[0];
  const float* seg = (const float*)d_in[1];
  const float* Wc  = (const float*)d_in[2];
  const float* bc  = (const float*)d_in[3];
  const float* Wfc = (const float*)d_in[4];
  const float* bfc = (const float*)d_in[5];
  const float* Wsc = (const float*)d_in[6];
  const float* bs  = (const float*)d_in[7];
  const float* Wrg = (const float*)d_in[8];
  const float* br  = (const float*)d_in[9];
  const float* Wi  = (const float*)d_in[10];
  const float* bi  = (const float*)d_in[11];
  const float* Wo  = (const float*)d_in[12];
  const float* bo  = (const float*)d_in[13];

  const size_t SZ_WCT = 2359296ull, SZ_WFT = 2097152ull, SZ_WIB = 36864ull,
               SZ_PART = 2097152ull, SZ_SC = 262144ull, SZ_CR = 262144ull,
               SZ_NB = 131072ull, SZ_STB = 4096ull, SZ_CI = CANDCAP * 4ull,
               SZ_SB = CANDCAP * 8ull, SZ_RY = CANDCAP * 8ull,
               SZ_RX = CANDCAP * 8ull, SZ_CY = 16384ull, SZ_CX = 16384ull,
               SZ_X1G = (size_t)CANDCAP * 1024ull * 8ull,   // 33.5 MB, own slot
               SZ_CNT = 256ull;
  const size_t FIXED = SZ_WCT + SZ_WFT + SZ_WIB + SZ_PART + SZ_SC + SZ_CR +
                       SZ_NB + SZ_STB + SZ_CI + SZ_SB + SZ_RY + SZ_RX +
                       SZ_CY + SZ_CX + SZ_X1G + SZ_CNT;
  char* w = (char*)d_ws;
  size_t region = (ws_size > FIXED) ? ((ws_size - FIXED) & ~(size_t)255) : 0;
  char* fb = w + region;
  unsigned short* WcT = (unsigned short*)fb;   fb += SZ_WCT;
  unsigned short* WfcT = (unsigned short*)fb;  fb += SZ_WFT;
  unsigned short* WiB = (unsigned short*)fb;   fb += SZ_WIB;
  float* part = (float*)fb;                    fb += SZ_PART;
  float* scores = (float*)fb;                  fb += SZ_SC;
  unsigned int* cellrank = (unsigned int*)fb;  fb += SZ_CR;
  unsigned int* nbrg = (unsigned int*)fb;      fb += SZ_NB;
  int* startb = (int*)fb;                      fb += SZ_STB;
  unsigned int* cand_idx = (unsigned int*)fb;  fb += SZ_CI;
  unsigned long long* cand_sb = (unsigned long long*)fb; fb += SZ_SB;
  double* cand_ry = (double*)fb;               fb += SZ_RY;
  double* cand_rx = (double*)fb;               fb += SZ_RX;
  double* cyg = (double*)fb;                   fb += SZ_CY;
  double* cxg = (double*)fb;                   fb += SZ_CX;
  double* x1g = (double*)fb;                   fb += SZ_X1G;
  unsigned int* cand_cnt = (unsigned int*)fb;
  unsigned short* x1b = (unsigned short*)w;    // big region: bf16 x1 chunk
  unsigned short* hb = (unsigned short*)w;     // big region: bf16 inst crops

  size_t tiles_fit = region / 131072ull;
  int pt_chunk = 2;
  while ((size_t)(pt_chunk * 2) <= tiles_fit && pt_chunk < 1024) pt_chunk <<= 1;
  size_t inst_fit = region / 294912ull;        // 48*48*64*2B per instance
  const int opts[12] = {500, 250, 125, 100, 50, 25, 20, 10, 5, 4, 2, 1};
  int inst_chunk = 1;
  for (int o = 0; o < 12; ++o)
    if ((size_t)opts[o] <= inst_fit) { inst_chunk = opts[o]; break; }

  float* out = (float*)d_out;
  float* out_ps  = out;
  float* out_dec = out + 500;
  float* out_io  = out + 1500;
  float* out_ic  = out + 1153500;

  transpose_bf16_kernel<<<dim3(36, 32), 256, 0, stream>>>(Wc, WcT, 1152, 1024);
  transpose_bf16_kernel<<<dim3(32, 32), 256, 0, stream>>>(Wfc, WfcT, 1024, 1024);
  prep_wib_kernel<<<72, 256, 0, stream>>>(Wi, WiB);

  for (int c = 0; c < 1024 / pt_chunk; ++c) {
    conv1_mfma<<<dim3(8, pt_chunk / 2), 256, 0, stream>>>(df, WcT, bc, x1b,
                                                          c * pt_chunk);
    fc_mfma<<<dim3(8, pt_chunk / 2), 256, 0, stream>>>(x1b, WfcT, bfc, Wsc,
                                                       part, c * pt_chunk);
  }
  head_finalize_kernel<<<256, 256, 0, stream>>>(part, bs, scores);
  select_kernel<<<1, 1024, 0, stream>>>(scores, cand_idx, cand_cnt);
  rescore_conv<<<CANDCAP / RC2, 1024, 0, stream>>>(df, Wc, bc, cand_idx,
                                                   cand_cnt, x1g);
  rescore_fc<<<CANDCAP / RC2, 1024, 0, stream>>>(x1g, Wfc, bfc, Wsc, bs, Wrg,
                                                 br, cand_cnt, cand_sb,
                                                 cand_ry, cand_rx);
  proposal_kernel<<<1, 1024, 0, stream>>>(cand_idx, cand_cnt, cand_sb, cand_ry,
                                          cand_rx, cellrank, nbrg, cyg, cxg,
                                          startb, out_ps, out_dec);
  for (int c = 0; c < 500 / inst_chunk; ++c) {
    conv_i_mfma<<<dim3(6, inst_chunk), 256, 0, stream>>>(seg, WiB, bi, startb,
                                                         hb, c * inst_chunk);
    conv_o_kernel<<<dim3(9, inst_chunk), 256, 0, stream>>>(hb, Wo, bo, startb,
                                                           out_io, out_ic,
                                                           c * inst_chunk);
  }
}

// Round 10
// 1550.716 us; speedup vs baseline: 1.4084x; 1.4084x over previous
//
#include <hip/hip_runtime.h>
#include <math.h>

#define KTOP 2000
#define MAXOUT 500
#define CANDCAP 4096          // candidate capacity (global buffers)
#define NSEL 3600             // approx-score rank margin for selection
#define RC2 16                // candidates per rescore block (256 groups)

typedef __attribute__((ext_vector_type(8))) short short8;
typedef __attribute__((ext_vector_type(4))) float f32x4;
typedef __attribute__((ext_vector_type(4))) double f64x4;

__device__ __forceinline__ unsigned short f2bf(float f) {
  unsigned int u = __float_as_uint(f);
  unsigned int r = ((u >> 16) & 1u) + 0x7FFFu;
  return (unsigned short)((u + r) >> 16);
}

// ---------------------------------------------------------------------------
// transpose+convert: W[K][N] f32 -> WT[N][K] bf16.  grid (K/32, N/32), 256 thr
// ---------------------------------------------------------------------------
__global__ __launch_bounds__(256) void transpose_bf16_kernel(
    const float* __restrict__ W, unsigned short* __restrict__ WT, int K, int N)
{
  __shared__ float t[32][33];
  const int k0 = blockIdx.x << 5, n0 = blockIdx.y << 5;
  const int tid = threadIdx.x;
  const int r = tid >> 5, c = tid & 31;
#pragma unroll
  for (int p = 0; p < 4; ++p)
    t[r + (p << 3)][c] = W[(size_t)(k0 + r + (p << 3)) * N + n0 + c];
  __syncthreads();
#pragma unroll
  for (int p = 0; p < 4; ++p)
    WT[(size_t)(n0 + r + (p << 3)) * K + k0 + c] = f2bf(t[c][r + (p << 3)]);
}

// ---------------------------------------------------------------------------
// prep WiB: Wi[288][64] f32 -> WiB[tap(9)][co(64)][ci(32)] bf16
// ---------------------------------------------------------------------------
__global__ __launch_bounds__(256) void prep_wib_kernel(
    const float* __restrict__ Wi, unsigned short* __restrict__ WiB)
{
  const int t = blockIdx.x * 256 + threadIdx.x;
  if (t < 9 * 64 * 32) {
    const int tap = t / 2048, r = t & 2047, co = r >> 5, ci = r & 31;
    WiB[t] = f2bf(Wi[((size_t)tap * 32 + ci) * 64 + co]);
  }
}

// ---------------------------------------------------------------------------
// conv1 via bf16 MFMA: 3x3 128->1024 + bias + relu -> x1b (bf16, chunk-local)
// ---------------------------------------------------------------------------
#define LSTR 72   // LDS row stride in bf16 elements (144 B)
__global__ __launch_bounds__(256) void conv1_mfma(
    const float* __restrict__ df, const unsigned short* __restrict__ WcT,
    const float* __restrict__ bc, unsigned short* __restrict__ x1b, int pt0)
{
  __shared__ __align__(16) unsigned short As[128 * LSTR];
  __shared__ __align__(16) unsigned short Bs[128 * LSTR];
  const int tid = threadIdx.x;
  const int n0 = blockIdx.x << 7;
  const int m0 = blockIdx.y << 7;
  const int Pbase = (pt0 << 6) + m0;
  const int ybase = Pbase >> 8, x0 = Pbase & 255;
  const int wv = tid >> 6, lane = tid & 63;
  const int wm = (wv & 1) << 6, wn = (wv >> 1) << 6;
  const int l15 = lane & 15, quad = lane >> 4;

  f32x4 acc[4][4];
  const f32x4 z4 = {0.f, 0.f, 0.f, 0.f};
#pragma unroll
  for (int i = 0; i < 4; ++i)
#pragma unroll
    for (int j = 0; j < 4; ++j) acc[i][j] = z4;

  for (int kc = 0; kc < 18; ++kc) {
    const int tap = kc >> 1, ci0 = (kc & 1) << 6;
    const int dy = tap / 3 - 1, dx = tap % 3 - 1;
    const int gy = ybase + dy;
    const bool yok = (gy >= 0 && gy < 256);
#pragma unroll
    for (int p = 0; p < 8; ++p) {
      const int r = (p << 4) + (tid >> 4);
      const int c4 = tid & 15;
      const int gx = x0 + r + dx;
      float4 v = make_float4(0.f, 0.f, 0.f, 0.f);
      if (yok && gx >= 0 && gx < 256)
        v = *(const float4*)&df[((size_t)((gy << 8) + gx)) * 128 + ci0 + (c4 << 2)];
      const unsigned int lo = (unsigned int)f2bf(v.x) | ((unsigned int)f2bf(v.y) << 16);
      const unsigned int hi = (unsigned int)f2bf(v.z) | ((unsigned int)f2bf(v.w) << 16);
      *(uint2*)&As[r * LSTR + (c4 << 2)] = make_uint2(lo, hi);
    }
#pragma unroll
    for (int p = 0; p < 4; ++p) {
      const int n = (p << 5) + (tid >> 3);
      const int kg = (tid & 7) << 3;
      const uint4 w = *(const uint4*)&WcT[(size_t)(n0 + n) * 1152 + kc * 64 + kg];
      *(uint4*)&Bs[n * LSTR + kg] = w;
    }
    __syncthreads();
#pragma unroll
    for (int s = 0; s < 2; ++s) {
      short8 a[4], b[4];
#pragma unroll
      for (int i = 0; i < 4; ++i)
        a[i] = *(short8*)&As[(wm + (i << 4) + l15) * LSTR + (s << 5) + (quad << 3)];
#pragma unroll
      for (int i = 0; i < 4; ++i)
        b[i] = *(short8*)&Bs[(wn + (i << 4) + l15) * LSTR + (s << 5) + (quad << 3)];
#pragma unroll
      for (int i = 0; i < 4; ++i)
#pragma unroll
        for (int j = 0; j < 4; ++j)
          acc[i][j] = __builtin_amdgcn_mfma_f32_16x16x32_bf16(a[i], b[j], acc[i][j], 0, 0, 0);
    }
    __syncthreads();
  }
#pragma unroll
  for (int i = 0; i < 4; ++i)
#pragma unroll
    for (int j = 0; j < 4; ++j) {
      const int col = wn + (j << 4) + l15;
      const float bb = bc[n0 + col];
#pragma unroll
      for (int rg = 0; rg < 4; ++rg) {
        const int row = wm + (i << 4) + (quad << 2) + rg;
        const float v = fmaxf(acc[i][j][rg] + bb, 0.f);
        x1b[(size_t)(m0 + row) * 1024 + n0 + col] = f2bf(v);
      }
    }
}

// ---------------------------------------------------------------------------
// fc via bf16 MFMA: 1x1 1024->1024 + bias + relu, fused score partials.
// ---------------------------------------------------------------------------
__global__ __launch_bounds__(256) void fc_mfma(
    const unsigned short* __restrict__ x1b, const unsigned short* __restrict__ WfcT,
    const float* __restrict__ bfc, const float* __restrict__ Wsc,
    float* __restrict__ part, int pt0)
{
  __shared__ __align__(16) unsigned short As[128 * LSTR];
  __shared__ __align__(16) unsigned short Bs[128 * LSTR];
  const int tid = threadIdx.x;
  const int n0 = blockIdx.x << 7;
  const int m0 = blockIdx.y << 7;
  const int Pbase = (pt0 << 6) + m0;
  const int wv = tid >> 6, lane = tid & 63;
  const int wm = (wv & 1) << 6, wn = (wv >> 1) << 6;
  const int l15 = lane & 15, quad = lane >> 4;

  f32x4 acc[4][4];
  const f32x4 z4 = {0.f, 0.f, 0.f, 0.f};
#pragma unroll
  for (int i = 0; i < 4; ++i)
#pragma unroll
    for (int j = 0; j < 4; ++j) acc[i][j] = z4;

  for (int kc = 0; kc < 16; ++kc) {
#pragma unroll
    for (int p = 0; p < 4; ++p) {
      const int r = (p << 5) + (tid >> 3);
      const int kg = (tid & 7) << 3;
      const uint4 w = *(const uint4*)&x1b[(size_t)(m0 + r) * 1024 + kc * 64 + kg];
      *(uint4*)&As[r * LSTR + kg] = w;
    }
#pragma unroll
    for (int p = 0; p < 4; ++p) {
      const int n = (p << 5) + (tid >> 3);
      const int kg = (tid & 7) << 3;
      const uint4 w = *(const uint4*)&WfcT[(size_t)(n0 + n) * 1024 + kc * 64 + kg];
      *(uint4*)&Bs[n * LSTR + kg] = w;
    }
    __syncthreads();
#pragma unroll
    for (int s = 0; s < 2; ++s) {
      short8 a[4], b[4];
#pragma unroll
      for (int i = 0; i < 4; ++i)
        a[i] = *(short8*)&As[(wm + (i << 4) + l15) * LSTR + (s << 5) + (quad << 3)];
#pragma unroll
      for (int i = 0; i < 4; ++i)
        b[i] = *(short8*)&Bs[(wn + (i << 4) + l15) * LSTR + (s << 5) + (quad << 3)];
#pragma unroll
      for (int i = 0; i < 4; ++i)
#pragma unroll
        for (int j = 0; j < 4; ++j)
          acc[i][j] = __builtin_amdgcn_mfma_f32_16x16x32_bf16(a[i], b[j], acc[i][j], 0, 0, 0);
    }
    __syncthreads();
  }
  float wsv[4], bfv[4];
#pragma unroll
  for (int j = 0; j < 4; ++j) {
    const int col = n0 + wn + (j << 4) + l15;
    wsv[j] = Wsc[col];
    bfv[j] = bfc[col];
  }
  float* red = (float*)As;
#pragma unroll
  for (int i = 0; i < 4; ++i)
#pragma unroll
    for (int rg = 0; rg < 4; ++rg) {
      const int row = wm + (i << 4) + (quad << 2) + rg;
      float ps = 0.f;
#pragma unroll
      for (int j = 0; j < 4; ++j) {
        const float v = fmaxf(acc[i][j][rg] + bfv[j], 0.f);
        ps = fmaf(v, wsv[j], ps);
      }
      red[row * 33 + ((wv >> 1) << 4) + l15] = ps;
    }
  __syncthreads();
  if (tid < 128) {
    float s = 0.f;
#pragma unroll
    for (int sl = 0; sl < 32; ++sl) s += red[tid * 33 + sl];
    part[(size_t)blockIdx.x * 65536 + Pbase + tid] = s;
  }
}

// ---------------------------------------------------------------------------
// finalize: sum 8 partials, bias, sigmoid -> f32 approx scores (selection)
// ---------------------------------------------------------------------------
__global__ __launch_bounds__(256) void head_finalize_kernel(
    const float* __restrict__ part, const float* __restrict__ bs,
    float* __restrict__ scores)
{
  const int pix = blockIdx.x * 256 + threadIdx.x;
  float s = 0.f;
#pragma unroll
  for (int cb = 0; cb < 8; ++cb) s += part[(size_t)cb * 65536 + pix];
  s += bs[0];
  scores[pix] = 1.f / (1.f + expf(-s));
}

// ---------------------------------------------------------------------------
// select: radix-select NSEL-th approx score, then DETERMINISTIC prefix-scan
// compaction of all cells >= thr in ascending cell order (no atomics).
// ---------------------------------------------------------------------------
__global__ __launch_bounds__(1024) void select_kernel(
    const float* __restrict__ scores, unsigned int* __restrict__ cand_idx,
    unsigned int* __restrict__ cand_cnt)
{
  __shared__ unsigned int hist[256];
  __shared__ unsigned int sh_prefix;
  __shared__ int scan_s[1024];
  const int tid = threadIdx.x;

  unsigned int prefix = 0u;
  int need = NSEL;
  for (int byte = 3; byte >= 0; --byte) {
    if (tid < 256) hist[tid] = 0u;
    __syncthreads();
    const int sh = byte * 8;
    const unsigned int mhi = (byte == 3) ? 0u : (0xFFFFFFFFu << (sh + 8));
    for (int i = tid; i < 65536; i += 1024) {
      const unsigned int b = __float_as_uint(scores[i]);
      if ((b & mhi) == prefix) atomicAdd(&hist[(b >> sh) & 255u], 1u);
    }
    __syncthreads();
    if (tid == 0) {
      int cum = 0;
      for (int v = 255; v >= 0; --v) {
        const int c = (int)hist[v];
        if (cum + c >= need) { sh_prefix = prefix | ((unsigned)v << sh); break; }
        cum += c;
      }
      hist[0] = (unsigned int)cum;
    }
    __syncthreads();
    prefix = sh_prefix;
    need -= (int)hist[0];
    __syncthreads();
  }
  const float thr = __uint_as_float(prefix);

  // deterministic compaction: thread t owns cells [t*64, t*64+64)
  const int b0 = tid << 6;
  int my = 0;
  for (int k = 0; k < 64; ++k)
    if (scores[b0 + k] >= thr) ++my;
  scan_s[tid] = my;
  __syncthreads();
  for (int off = 1; off < 1024; off <<= 1) {
    const int a = scan_s[tid];
    const int b = (tid >= off) ? scan_s[tid - off] : 0;
    __syncthreads();
    scan_s[tid] = a + b;
    __syncthreads();
  }
  int pos = scan_s[tid] - my;     // exclusive prefix
  const int total = scan_s[1023];
  for (int k = 0; k < 64; ++k) {
    if (scores[b0 + k] >= thr) {
      if (pos < CANDCAP) cand_idx[pos] = (unsigned int)(b0 + k);
      ++pos;
    }
  }
  if (tid == 0)
    *cand_cnt = (unsigned int)(total > CANDCAP ? CANDCAP : total);
}

// ---------------------------------------------------------------------------
// rescore_conv via f64 MFMA (v_mfma_f64_16x16x4f64): M=16 cand, N=1024 co,
// K=1152.  512 thr (8 waves, wave owns 128 co as 8 16-wide tiles).
// A: lane = m + 16*k (m=cand); B: lane = n + 16*k; D: col=lane&15,
// row=(lane>>4)*4+reg.  Weight traffic unchanged (4.7 MB/block).
// ---------------------------------------------------------------------------
#define PSTR 133   // f64 LDS row stride (conflict-free for quad-strided b64)
__global__ __launch_bounds__(512) void rescore_conv(
    const float* __restrict__ df, const float* __restrict__ Wc,
    const float* __restrict__ bc,
    const unsigned int* __restrict__ cand_idx,
    const unsigned int* __restrict__ cand_cnt,
    double* __restrict__ x1g)
{
  __shared__ double patt[16 * PSTR];   // 17 KB
  __shared__ int rrs[16], ccs[16];
  const int cnt = (int)*cand_cnt;
  const int c0 = blockIdx.x * RC2;
  if (c0 >= cnt) return;
  const int tid = threadIdx.x;
  const int wv = tid >> 6, lane = tid & 63;
  const int m = lane & 15, quad = lane >> 4;
  const int co_base = wv << 7;

  if (tid < 16) {
    const int slot = (c0 + tid < cnt) ? c0 + tid : c0;
    const unsigned int idx = cand_idx[slot];
    rrs[tid] = (int)(idx >> 8); ccs[tid] = (int)(idx & 255u);
  }

  f64x4 acc[8];
  const f64x4 z4 = {0.0, 0.0, 0.0, 0.0};
#pragma unroll
  for (int t = 0; t < 8; ++t) acc[t] = z4;

  for (int tap = 0; tap < 9; ++tap) {
    const int dy = tap / 3 - 1, dx = tap % 3 - 1;
    __syncthreads();
    for (int p = tid; p < 2048; p += 512) {
      const int c = p >> 7, ci = p & 127;
      const int gy = rrs[c] + dy, gx = ccs[c] + dx;
      float v = 0.f;
      if (gy >= 0 && gy < 256 && gx >= 0 && gx < 256)
        v = df[((size_t)((gy << 8) + gx)) * 128 + ci];
      patt[c * PSTR + ci] = (double)v;
    }
    __syncthreads();
    const float* wrow = &Wc[(size_t)(tap * 128 + quad) * 1024 + co_base + m];
    float wf[8];
#pragma unroll
    for (int t = 0; t < 8; ++t) wf[t] = wrow[t << 4];
    for (int k4 = 0; k4 < 32; ++k4) {
      float wn[8];
      if (k4 + 1 < 32) {
#pragma unroll
        for (int t = 0; t < 8; ++t)
          wn[t] = wrow[(size_t)((k4 + 1) << 2) * 1024 + (t << 4)];
      }
      const double a = patt[m * PSTR + (k4 << 2) + quad];
#pragma unroll
      for (int t = 0; t < 8; ++t)
        acc[t] = __builtin_amdgcn_mfma_f64_16x16x4f64(a, (double)wf[t], acc[t], 0, 0, 0);
      if (k4 + 1 < 32) {
#pragma unroll
        for (int t = 0; t < 8; ++t) wf[t] = wn[t];
      }
    }
  }
  // epilogue: lane holds D[cand = 4*quad+reg][co = co_base + t*16 + m]
#pragma unroll
  for (int t = 0; t < 8; ++t) {
    const int co = co_base + (t << 4) + m;
    const double bb = (double)bc[co];
#pragma unroll
    for (int rg = 0; rg < 4; ++rg) {
      const int cand = (quad << 2) + rg;
      if (c0 + cand < cnt) {
        const double v = acc[t][rg] + bb;
        x1g[(size_t)(c0 + cand) * 1024 + co] = v > 0.0 ? v : 0.0;
      }
    }
  }
}

// ---------------------------------------------------------------------------
// rescore_fc via f64 MFMA: M=16 cand, N=1024, K=1024; heads fused with
// deterministic butterfly + fixed-order wave combine.  512 thr.
// ---------------------------------------------------------------------------
__global__ __launch_bounds__(512) void rescore_fc(
    const double* __restrict__ x1g, const float* __restrict__ Wfc,
    const float* __restrict__ bfc, const float* __restrict__ Wsc,
    const float* __restrict__ bs, const float* __restrict__ Wrg,
    const float* __restrict__ br,
    const unsigned int* __restrict__ cand_cnt,
    unsigned long long* __restrict__ cand_sb,
    double* __restrict__ cand_ry, double* __restrict__ cand_rx)
{
  __shared__ double xbuf[16 * PSTR];   // 17 KB
  __shared__ double partw[3][8][16];   // [head][wave][cand], 3 KB
  const int cnt = (int)*cand_cnt;
  const int c0 = blockIdx.x * RC2;
  if (c0 >= cnt) return;
  const int tid = threadIdx.x;
  const int wv = tid >> 6, lane = tid & 63;
  const int m = lane & 15, quad = lane >> 4;
  const int co_base = wv << 7;

  f64x4 acc[8];
  const f64x4 z4 = {0.0, 0.0, 0.0, 0.0};
#pragma unroll
  for (int t = 0; t < 8; ++t) acc[t] = z4;

  for (int kc = 0; kc < 8; ++kc) {
    __syncthreads();
    for (int p = tid; p < 2048; p += 512) {
      const int c = p >> 7, k = p & 127;
      const int row = (c0 + c < cnt) ? c0 + c : c0;
      xbuf[c * PSTR + k] = x1g[(size_t)row * 1024 + (kc << 7) + k];
    }
    __syncthreads();
    const float* wrow = &Wfc[(size_t)((kc << 7) + quad) * 1024 + co_base + m];
    float wf[8];
#pragma unroll
    for (int t = 0; t < 8; ++t) wf[t] = wrow[t << 4];
    for (int k4 = 0; k4 < 32; ++k4) {
      float wn[8];
      if (k4 + 1 < 32) {
#pragma unroll
        for (int t = 0; t < 8; ++t)
          wn[t] = wrow[(size_t)((k4 + 1) << 2) * 1024 + (t << 4)];
      }
      const double a = xbuf[m * PSTR + (k4 << 2) + quad];
#pragma unroll
      for (int t = 0; t < 8; ++t)
        acc[t] = __builtin_amdgcn_mfma_f64_16x16x4f64(a, (double)wf[t], acc[t], 0, 0, 0);
      if (k4 + 1 < 32) {
#pragma unroll
        for (int t = 0; t < 8; ++t) wf[t] = wn[t];
      }
    }
  }

  // heads: per lane, 4 cands (reg) x 8 co (t)
  double ps[4] = {0, 0, 0, 0}, py[4] = {0, 0, 0, 0}, px[4] = {0, 0, 0, 0};
#pragma unroll
  for (int t = 0; t < 8; ++t) {
    const int co = co_base + (t << 4) + m;
    const double bfv = (double)bfc[co];
    const double wsv = (double)Wsc[co];
    const double w0 = (double)Wrg[co * 2], w1 = (double)Wrg[co * 2 + 1];
#pragma unroll
    for (int rg = 0; rg < 4; ++rg) {
      double v = acc[t][rg] + bfv;
      v = v > 0.0 ? v : 0.0;
      ps[rg] = fma(v, wsv, ps[rg]);
      py[rg] = fma(v, w0, py[rg]);
      px[rg] = fma(v, w1, px[rg]);
    }
  }
  // butterfly over the 16 m-lanes (xor 1,2,4,8) — deterministic fixed order
#pragma unroll
  for (int off = 1; off <= 8; off <<= 1) {
#pragma unroll
    for (int rg = 0; rg < 4; ++rg) {
      ps[rg] += __shfl_xor(ps[rg], off, 64);
      py[rg] += __shfl_xor(py[rg], off, 64);
      px[rg] += __shfl_xor(px[rg], off, 64);
    }
  }
  if (m == 0) {
#pragma unroll
    for (int rg = 0; rg < 4; ++rg) {
      const int cand = (quad << 2) + rg;
      partw[0][wv][cand] = ps[rg];
      partw[1][wv][cand] = py[rg];
      partw[2][wv][cand] = px[rg];
    }
  }
  __syncthreads();
  if (tid < 48) {
    const int cand = tid & 15, h = tid >> 4;
    double s = 0.0;
#pragma unroll
    for (int w8 = 0; w8 < 8; ++w8) s += partw[h][w8][cand];
    if (c0 + cand < cnt) {
      if (h == 0) {
        const double lg = s + (double)bs[0];
        const double sg = 1.0 / (1.0 + exp(-lg));
        cand_sb[c0 + cand] = (unsigned long long)__double_as_longlong(sg);
      } else if (h == 1) cand_ry[c0 + cand] = s + (double)br[0];
      else               cand_rx[c0 + cand] = s + (double)br[1];
    }
  }
}

// ---------------------------------------------------------------------------
// proposal: f64 radix-select top-2000, DETERMINISTIC compaction (ascending
// slot = ascending cell), bitonic sort with (score desc, slot asc) tie-break,
// f64 NMS, emit.  Single block, 1024 threads.
// ---------------------------------------------------------------------------
__global__ __launch_bounds__(1024) void proposal_kernel(
    const unsigned int* __restrict__ cand_idx,
    const unsigned int* __restrict__ cand_cnt,
    const unsigned long long* __restrict__ cand_sb,
    const double* __restrict__ cand_ry, const double* __restrict__ cand_rx,
    unsigned int* __restrict__ cellrank, unsigned int* __restrict__ nbrg,
    double* __restrict__ cyg, double* __restrict__ cxg,
    int* __restrict__ startb, float* __restrict__ out_ps,
    float* __restrict__ out_dec)
{
  __shared__ unsigned long long sk[2048];
  __shared__ unsigned int si[2048];
  __shared__ unsigned int hist[256];
  __shared__ unsigned long long sh_pref;
  __shared__ unsigned char kept[2048];
  __shared__ unsigned char nbrc[2048];
  __shared__ int scan[2048];
  __shared__ volatile unsigned int changed;
  __shared__ int sh_maxreg;

  const int tid = threadIdx.x;
  const int cnt = (int)*cand_cnt;

  for (int i = tid; i < 65536; i += 1024) cellrank[i] = 0xFFFFFFFFu;

  // ---- radix-select the 2000th-largest f64-score bit pattern
  unsigned long long prefix = 0ull;
  int need = KTOP;
  for (int byte = 7; byte >= 0; --byte) {
    if (tid < 256) hist[tid] = 0u;
    __syncthreads();
    const int sh = byte * 8;
    const unsigned long long mhi =
        (byte == 7) ? 0ull : (0xFFFFFFFFFFFFFFFFull << (sh + 8));
    for (int i = tid; i < cnt; i += 1024) {
      const unsigned long long k = cand_sb[i];
      if ((k & mhi) == prefix) atomicAdd(&hist[(unsigned int)((k >> sh) & 255u)], 1u);
    }
    __syncthreads();
    if (tid == 0) {
      int cum = 0;
      for (int v = 255; v >= 0; --v) {
        const int c = (int)hist[v];
        if (cum + c >= need) {
          sh_pref = prefix | ((unsigned long long)(unsigned)v << sh);
          break;
        }
        cum += c;
      }
      hist[0] = (unsigned int)cum;
    }
    __syncthreads();
    prefix = sh_pref;
    need -= (int)hist[0];
    __syncthreads();
  }
  const unsigned long long T = prefix;

  // ---- deterministic compaction: thread t owns slots [4t, 4t+4)
  const int s0 = tid << 2;
  unsigned long long kv[4];
  int ca = 0, cb = 0;
#pragma unroll
  for (int q = 0; q < 4; ++q) {
    const int s = s0 + q;
    kv[q] = (s < cnt) ? cand_sb[s] : 0ull;
    if (s < cnt) { if (kv[q] > T) ++ca; else if (kv[q] == T) ++cb; }
  }
  scan[tid] = ca;
  __syncthreads();
  for (int off = 1; off < 1024; off <<= 1) {
    const int a = scan[tid];
    const int b = (tid >= off) ? scan[tid - off] : 0;
    __syncthreads();
    scan[tid] = a + b;
    __syncthreads();
  }
  int posA = scan[tid] - ca;         // exclusive
  const int atot = scan[1023];
  __syncthreads();
  scan[tid] = cb;
  __syncthreads();
  for (int off = 1; off < 1024; off <<= 1) {
    const int a = scan[tid];
    const int b = (tid >= off) ? scan[tid - off] : 0;
    __syncthreads();
    scan[tid] = a + b;
    __syncthreads();
  }
  int posB = atot + (scan[tid] - cb);
  __syncthreads();
#pragma unroll
  for (int q = 0; q < 4; ++q) {
    const int s = s0 + q;
    if (s < cnt) {
      if (kv[q] > T) {
        sk[posA] = kv[q]; si[posA] = (unsigned int)s; ++posA;
      } else if (kv[q] == T) {
        if (posB < KTOP) { sk[posB] = kv[q]; si[posB] = (unsigned int)s; }
        ++posB;
      }
    }
  }
  __syncthreads();
  for (int i = tid; i < 2048; i += 1024)
    if (i >= KTOP) { sk[i] = 0ull; si[i] = 0u; }
  if (tid == 0) sh_maxreg = 0;
  __syncthreads();

  // ---- bitonic sort 2048 descending by (score bits, then ascending slot)
  for (int k = 2; k <= 2048; k <<= 1) {
    for (int j = k >> 1; j > 0; j >>= 1) {
      const int i = (tid & (j - 1)) | ((tid & ~(j - 1)) << 1);
      const int ixj = i | j;
      const unsigned long long a = sk[i], b = sk[ixj];
      const unsigned int ia = si[i], ib = si[ixj];
      const bool up = ((i & k) == 0);
      const bool lt = (a < b) || (a == b && ia > ib);
      const bool gt = (a > b) || (a == b && ia < ib);
      if (up ? lt : gt) {
        sk[i] = b; sk[ixj] = a;
        si[i] = ib; si[ixj] = ia;
      }
      __syncthreads();
    }
  }

  // ---- decode top-2000 (f64)
  for (int r = tid; r < KTOP; r += 1024) {
    const unsigned int slot = si[r];
    const unsigned int idx = cand_idx[slot];
    const int row = (int)(idx >> 8), col = (int)(idx & 255u);
    const double ry = cand_ry[slot], rx = cand_rx[slot];
    cyg[r] = ((double)row + 0.5) + ry;
    cxg[r] = ((double)col + 0.5) + rx;
    kept[r] = 1; nbrc[r] = 0;
    cellrank[idx] = (unsigned int)r;
    atomicMax(&sh_maxreg, __float_as_int((float)fabs(ry)));
    atomicMax(&sh_maxreg, __float_as_int((float)fabs(rx)));
  }
  __syncthreads();
  const float maxreg = __int_as_float(sh_maxreg);
  int rad = (int)(1.0f + 2.0f * maxreg) + 1;
  if (rad > 8) rad = 8;
  if (rad < 1) rad = 1;

  // ---- earlier-close neighbor lists (f64 distances, no contraction)
  for (int r = tid; r < KTOP; r += 1024) {
    const unsigned int idx = cand_idx[si[r]];
    const int row = (int)(idx >> 8), col = (int)(idx & 255u);
    int n = 0;
    const double pyr = cyg[r], pxr = cxg[r];
    for (int dy = -rad; dy <= rad; ++dy) {
      const int yy = row + dy; if (yy < 0 || yy >= 256) continue;
      for (int dx = -rad; dx <= rad; ++dx) {
        if (dy == 0 && dx == 0) continue;
        const int xx = col + dx; if (xx < 0 || xx >= 256) continue;
        const unsigned int q = cellrank[yy * 256 + xx];
        if (q < (unsigned int)r) {
          const double t1 = __dsub_rn(pyr, cyg[q]);
          const double t2 = __dsub_rn(pxr, cxg[q]);
          const double d2 = __dadd_rn(__dmul_rn(t1, t1), __dmul_rn(t2, t2));
          if (d2 < 1.0) { if (n < 16) nbrg[(size_t)r * 16 + n] = q; ++n; }
        }
      }
    }
    nbrc[r] = (unsigned char)(n < 16 ? n : 16);
  }
  __syncthreads();

  // ---- fixpoint == sequential NMS (unique fixpoint on rank-DAG)
  for (int it = 0; it < 4096; ++it) {
    __syncthreads();
    if (tid == 0) changed = 0;
    __syncthreads();
    for (int r = tid; r < KTOP; r += 1024) {
      const int nc = nbrc[r];
      if (nc) {
        int kvv = 1;
        for (int t = 0; t < nc; ++t)
          if (kept[nbrg[(size_t)r * 16 + t]]) { kvv = 0; break; }
        if (kvv != (int)kept[r]) { kept[r] = (unsigned char)kvv; changed = 1; }
      }
    }
    __syncthreads();
    if (changed == 0) break;
  }

  // ---- inclusive prefix scan of kept
  scan[tid]        = (tid < KTOP) ? (int)kept[tid] : 0;
  scan[tid + 1024] = (tid + 1024 < KTOP) ? (int)kept[tid + 1024] : 0;
  __syncthreads();
  for (int off = 1; off < 2048; off <<= 1) {
    const int a0 = scan[tid];
    const int b0 = (tid >= off) ? scan[tid - off] : 0;
    const int a1 = scan[tid + 1024];
    const int b1 = (tid + 1024 >= off) ? scan[tid + 1024 - off] : 0;
    __syncthreads();
    scan[tid] = a0 + b0;
    scan[tid + 1024] = a1 + b1;
    __syncthreads();
  }
  const int total = scan[KTOP - 1];

  // ---- emit
  for (int r = tid; r < KTOP; r += 1024) {
    int slot = -1;
    if (kept[r]) { const int p = scan[r] - 1; if (p < MAXOUT) slot = p; }
    else { const int p = total + (r - scan[r]); if (p < MAXOUT) slot = p; }
    if (slot >= 0) {
      const double sg = __longlong_as_double((long long)sk[r]);
      out_ps[slot] = kept[r] ? (float)sg : -1.0f;
      const double py = cyg[r], px = cxg[r];
      out_dec[slot * 2]     = (float)(py * 4.0);
      out_dec[slot * 2 + 1] = (float)(px * 4.0);
      int sy = (int)rint(py * 2.0 - 24.0);
      int sx = (int)rint(px * 2.0 - 24.0);
      sy = sy < 0 ? 0 : (sy > 464 ? 464 : sy);
      sx = sx < 0 ? 0 : (sx > 464 ? 464 : sx);
      startb[slot * 2] = sy; startb[slot * 2 + 1] = sx;
    }
  }
}

// ---------------------------------------------------------------------------
// conv_i via bf16 MFMA: 3x3 32->64 + relu on 48x48 crops -> h (bf16).
// ---------------------------------------------------------------------------
#define ISTR 40   // input pixel stride in bf16 elems (80 B)
__global__ __launch_bounds__(256) void conv_i_mfma(
    const float* __restrict__ seg, const unsigned short* __restrict__ WiB,
    const float* __restrict__ bi, const int* __restrict__ startb,
    unsigned short* __restrict__ h, int inst0)
{
  __shared__ __align__(16) unsigned short ins[500 * ISTR];   // 40 KB (reused)
  const int li = blockIdx.y;
  const int inst = inst0 + li;
  const int tile = blockIdx.x;              // 0..5
  const int r0 = tile << 3;
  const int tid = threadIdx.x;
  const int sy = startb[inst * 2], sx = startb[inst * 2 + 1];

  for (int p = tid; p < 500; p += 256) {
    const int rr = p / 50, cc2 = p - rr * 50;
    const int ir = r0 - 1 + rr, ic = cc2 - 1;
    unsigned short* dst = &ins[p * ISTR];
    if (ir >= 0 && ir < 48 && ic >= 0 && ic < 48) {
      const float* src = &seg[((size_t)(sy + ir) * 512 + (sx + ic)) * 32];
#pragma unroll
      for (int q = 0; q < 8; ++q) {
        const float4 v = *(const float4*)&src[q << 2];
        const unsigned int lo = (unsigned int)f2bf(v.x) | ((unsigned int)f2bf(v.y) << 16);
        const unsigned int hi = (unsigned int)f2bf(v.z) | ((unsigned int)f2bf(v.w) << 16);
        *(uint2*)&dst[q << 2] = make_uint2(lo, hi);
      }
    } else {
#pragma unroll
      for (int q = 0; q < 4; ++q) *(uint4*)&dst[q << 3] = make_uint4(0, 0, 0, 0);
    }
  }
  __syncthreads();

  const int wv = tid >> 6, lane = tid & 63;
  const int l15 = lane & 15, quad = lane >> 4;
  const int wmb = wv * 96;

  int pbase[6];
#pragma unroll
  for (int i = 0; i < 6; ++i) {
    const int m = wmb + (i << 4) + l15;
    pbase[i] = (m / 48 + 1) * 50 + (m % 48) + 1;
  }

  f32x4 acc[6][4];
  const f32x4 z4 = {0.f, 0.f, 0.f, 0.f};
#pragma unroll
  for (int i = 0; i < 6; ++i)
#pragma unroll
    for (int j = 0; j < 4; ++j) acc[i][j] = z4;

  for (int tap = 0; tap < 9; ++tap) {
    const int off = (tap / 3 - 1) * 50 + (tap % 3 - 1);
    short8 b[4];
#pragma unroll
    for (int j = 0; j < 4; ++j)
      b[j] = *(const short8*)&WiB[((tap << 6) + (j << 4) + l15) * 32 + (quad << 3)];
#pragma unroll
    for (int i = 0; i < 6; ++i) {
      const short8 a = *(const short8*)&ins[(pbase[i] + off) * ISTR + (quad << 3)];
#pragma unroll
      for (int j = 0; j < 4; ++j)
        acc[i][j] = __builtin_amdgcn_mfma_f32_16x16x32_bf16(a, b[j], acc[i][j], 0, 0, 0);
    }
  }

  float bv[4];
#pragma unroll
  for (int j = 0; j < 4; ++j) bv[j] = bi[(j << 4) + l15];

  for (int half = 0; half < 2; ++half) {
    __syncthreads();
    if ((wv >> 1) == half) {
#pragma unroll
      for (int i = 0; i < 6; ++i)
#pragma unroll
        for (int j = 0; j < 4; ++j)
#pragma unroll
          for (int rg = 0; rg < 4; ++rg) {
            const int m = wmb + (i << 4) + (quad << 2) + rg;
            const int pp = m - half * 192;
            const float v = fmaxf(acc[i][j][rg] + bv[j], 0.f);
            ins[pp * 72 + (j << 4) + l15] = f2bf(v);
          }
    }
    __syncthreads();
    for (int t = tid; t < 192 * 8; t += 256) {
      const int pp = t >> 3, c8 = t & 7;
      const uint4 v = *(const uint4*)&ins[pp * 72 + (c8 << 3)];
      *(uint4*)&h[((size_t)li * 2304 + (tile * 384 + half * 192 + pp)) * 64 + (c8 << 3)] = v;
    }
  }
}

// ---------------------------------------------------------------------------
// conv_o: 3x3, 64->1 + sigmoid on bf16 h; emits instance_coords.
// ---------------------------------------------------------------------------
__global__ __launch_bounds__(256) void conv_o_kernel(
    const unsigned short* __restrict__ h, const float* __restrict__ Wo,
    const float* __restrict__ bo, const int* __restrict__ startb,
    float* __restrict__ out_io, float* __restrict__ out_ic, int inst0)
{
  __shared__ __align__(16) unsigned short hs[324 * 72];   // 46.7 KB
  __shared__ float wos[576];
  const int li = blockIdx.y;
  const int inst = inst0 + li;
  const int tile = blockIdx.x;
  const int ty0 = (tile / 3) << 4;
  const int tx0 = (tile % 3) << 4;
  const int tid = threadIdx.x;

  for (int i = tid; i < 576; i += 256) wos[i] = Wo[i];
  for (int p = tid; p < 324; p += 256) {
    const int iy = p / 18, ix = p - iy * 18;
    const int gy = ty0 - 1 + iy, gx = tx0 - 1 + ix;
    unsigned short* dst = &hs[p * 72];
    if (gy >= 0 && gy < 48 && gx >= 0 && gx < 48) {
      const unsigned short* src = &h[((size_t)li * 2304 + gy * 48 + gx) * 64];
#pragma unroll
      for (int q = 0; q < 8; ++q) *(uint4*)&dst[q << 3] = *(const uint4*)&src[q << 3];
    } else {
#pragma unroll
      for (int q = 0; q < 8; ++q) *(uint4*)&dst[q << 3] = make_uint4(0, 0, 0, 0);
    }
  }
  __syncthreads();

  const int ly = tid >> 4, lx = tid & 15;
  float a = 0.f;
#pragma unroll
  for (int ky = 0; ky < 3; ++ky)
#pragma unroll
    for (int kx = 0; kx < 3; ++kx) {
      const unsigned short* hp = &hs[((ly + ky) * 18 + lx + kx) * 72];
      const float* wp = &wos[(ky * 3 + kx) << 6];
#pragma unroll
      for (int c8 = 0; c8 < 8; ++c8) {
        const uint4 hv = *(const uint4*)&hp[c8 << 3];
        const unsigned int uu[4] = {hv.x, hv.y, hv.z, hv.w};
#pragma unroll
        for (int e = 0; e < 4; ++e) {
          const float f0 = __uint_as_float(uu[e] << 16);
          const float f1 = __uint_as_float(uu[e] & 0xFFFF0000u);
          a = fmaf(f0, wp[(c8 << 3) + (e << 1)], a);
          a = fmaf(f1, wp[(c8 << 3) + (e << 1) + 1], a);
        }
      }
    }
  a += bo[0];
  const float o = 1.f / (1.f + expf(-a));
  const int gy = ty0 + ly, gx = tx0 + lx;
  const size_t p = ((size_t)inst * 48 + gy) * 48 + gx;
  out_io[p] = o;
  const int sy = startb[inst * 2], sx = startb[inst * 2 + 1];
  out_ic[p * 2]     = (float)(sy + gy);
  out_ic[p * 2 + 1] = (float)(sx + gx);
}

// ---------------------------------------------------------------------------
extern "C" void kernel_launch(void* const* d_in, const int* in_sizes, int n_in,
                              void* d_out, int out_size, void* d_ws, size_t ws_size,
                              hipStream_t stream)
{
  const float* df  = (const float*)d_in[0];
  const float* seg = (const float*)d_in[1];
  const float* Wc  = (const float*)d_in[2];
  const float* bc  = (const float*)d_in[3];
  const float* Wfc = (const float*)d_in[4];
  const float* bfc = (const float*)d_in[5];
  const float* Wsc = (const float*)d_in[6];
  const float* bs  = (const float*)d_in[7];
  const float* Wrg = (const float*)d_in[8];
  const float* br  = (const float*)d_in[9];
  const float* Wi  = (const float*)d_in[10];
  const float* bi  = (const float*)d_in[11];
  const float* Wo  = (const float*)d_in[12];
  const float* bo  = (const float*)d_in[13];

  const size_t SZ_WCT = 2359296ull, SZ_WFT = 2097152ull, SZ_WIB = 36864ull,
               SZ_PART = 2097152ull, SZ_SC = 262144ull, SZ_CR = 262144ull,
               SZ_NB = 131072ull, SZ_STB = 4096ull, SZ_CI = CANDCAP * 4ull,
               SZ_SB = CANDCAP * 8ull, SZ_RY = CANDCAP * 8ull,
               SZ_RX = CANDCAP * 8ull, SZ_CY = 16384ull, SZ_CX = 16384ull,
               SZ_X1G = (size_t)CANDCAP * 1024ull * 8ull,   // 33.5 MB, own slot
               SZ_CNT = 256ull;
  const size_t FIXED = SZ_WCT + SZ_WFT + SZ_WIB + SZ_PART + SZ_SC + SZ_CR +
                       SZ_NB + SZ_STB + SZ_CI + SZ_SB + SZ_RY + SZ_RX +
                       SZ_CY + SZ_CX + SZ_X1G + SZ_CNT;
  char* w = (char*)d_ws;
  size_t region = (ws_size > FIXED) ? ((ws_size - FIXED) & ~(size_t)255) : 0;
  char* fb = w + region;
  unsigned short* WcT = (unsigned short*)fb;   fb += SZ_WCT;
  unsigned short* WfcT = (unsigned short*)fb;  fb += SZ_WFT;
  unsigned short* WiB = (unsigned short*)fb;   fb += SZ_WIB;
  float* part = (float*)fb;                    fb += SZ_PART;
  float* scores = (float*)fb;                  fb += SZ_SC;
  unsigned int* cellrank = (unsigned int*)fb;  fb += SZ_CR;
  unsigned int* nbrg = (unsigned int*)fb;      fb += SZ_NB;
  int* startb = (int*)fb;                      fb += SZ_STB;
  unsigned int* cand_idx = (unsigned int*)fb;  fb += SZ_CI;
  unsigned long long* cand_sb = (unsigned long long*)fb; fb += SZ_SB;
  double* cand_ry = (double*)fb;               fb += SZ_RY;
  double* cand_rx = (double*)fb;               fb += SZ_RX;
  double* cyg = (double*)fb;                   fb += SZ_CY;
  double* cxg = (double*)fb;                   fb += SZ_CX;
  double* x1g = (double*)fb;                   fb += SZ_X1G;
  unsigned int* cand_cnt = (unsigned int*)fb;
  unsigned short* x1b = (unsigned short*)w;    // big region: bf16 x1 chunk
  unsigned short* hb = (unsigned short*)w;     // big region: bf16 inst crops

  size_t tiles_fit = region / 131072ull;
  int pt_chunk = 2;
  while ((size_t)(pt_chunk * 2) <= tiles_fit && pt_chunk < 1024) pt_chunk <<= 1;
  size_t inst_fit = region / 294912ull;        // 48*48*64*2B per instance
  const int opts[12] = {500, 250, 125, 100, 50, 25, 20, 10, 5, 4, 2, 1};
  int inst_chunk = 1;
  for (int o = 0; o < 12; ++o)
    if ((size_t)opts[o] <= inst_fit) { inst_chunk = opts[o]; break; }

  float* out = (float*)d_out;
  float* out_ps  = out;
  float* out_dec = out + 500;
  float* out_io  = out + 1500;
  float* out_ic  = out + 1153500;

  transpose_bf16_kernel<<<dim3(36, 32), 256, 0, stream>>>(Wc, WcT, 1152, 1024);
  transpose_bf16_kernel<<<dim3(32, 32), 256, 0, stream>>>(Wfc, WfcT, 1024, 1024);
  prep_wib_kernel<<<72, 256, 0, stream>>>(Wi, WiB);

  for (int c = 0; c < 1024 / pt_chunk; ++c) {
    conv1_mfma<<<dim3(8, pt_chunk / 2), 256, 0, stream>>>(df, WcT, bc, x1b,
                                                          c * pt_chunk);
    fc_mfma<<<dim3(8, pt_chunk / 2), 256, 0, stream>>>(x1b, WfcT, bfc, Wsc,
                                                       part, c * pt_chunk);
  }
  head_finalize_kernel<<<256, 256, 0, stream>>>(part, bs, scores);
  select_kernel<<<1, 1024, 0, stream>>>(scores, cand_idx, cand_cnt);
  rescore_conv<<<CANDCAP / RC2, 512, 0, stream>>>(df, Wc, bc, cand_idx,
                                                  cand_cnt, x1g);
  rescore_fc<<<CANDCAP / RC2, 512, 0, stream>>>(x1g, Wfc, bfc, Wsc, bs, Wrg,
                                                br, cand_cnt, cand_sb,
                                                cand_ry, cand_rx);
  proposal_kernel<<<1, 1024, 0, stream>>>(cand_idx, cand_cnt, cand_sb, cand_ry,
                                          cand_rx, cellrank, nbrg, cyg, cxg,
                                          startb, out_ps, out_dec);
  for (int c = 0; c < 500 / inst_chunk; ++c) {
    conv_i_mfma<<<dim3(6, inst_chunk), 256, 0, stream>>>(seg, WiB, bi, startb,
                                                         hb, c * inst_chunk);
    conv_o_kernel<<<dim3(9, inst_chunk), 256, 0, stream>>>(hb, Wo, bo, startb,
                                                           out_io, out_ic,
                                                           c * inst_chunk);
  }
}